// Round 16
// baseline (415.910 us; speedup 1.0000x reference)
//
#include <hip/hip_runtime.h>
#include <stdint.h>

// Problem: B=8, C=3, N=4096, K=20, C_OUT=64.
// out  = W[o] * mean_c(x[b,c,idx[b,n,j]])  -> (8,64,4096,20) f32, 168 MB
// idx_flat = top20 indices + b*N            -> (8*4096*20,) written as FLOAT
//
// Reference arithmetic model (round-12): expected outputs are JAX-CPU
// precomputed (jaxref_precompute_s) => match XLA-CPU. XLA lowers einsum ->
// dot_general -> Eigen gemm: k=3 FMA accumulation from 0:
//   dot = fma(a2,b2, fma(a1,b1, a0*b0)).
// xx = reduce(x*x) over 3 elems: plain sequential (s0+s1)+s2.
// neg_dist = -xx - inner - swapaxes(xx,1,2); xx is (B,1,N) so the FIRST
// term broadcasts to -||x_m||^2 (neighbor), LAST is -||x_n||^2 (query):
//   nd[n,m] = ((-xx_m) - inner[n,m]) - xx_n    (left-assoc, plain subs)
// inner = -2*dot (exact). Subtractions under contract(off) so hipcc can't
// fuse ((-p.w) - (-2*dot)) into fma(2,dot,-p.w).
// Round-14: fixed pragma placement (must open a compound statement).
//
// Kernel A: per-row (b,n) exact stable top-20 on bit-matched f32 keys.
// Kernel B: expands fm chunk across 64 output planes, coalesced float4.

#define NPTS 4096
#define KSEL 20
#define WAVES 8
#define THREADS (WAVES * 64)

__device__ __forceinline__ uint32_t ordf(float f) {
  uint32_t b = __float_as_uint(f);
  return b ^ (uint32_t)((((int32_t)b) >> 31) | 0x80000000);
}

__device__ __forceinline__ uint64_t shflx64(uint64_t v, int m) {
  int lo = __shfl_xor((int)(uint32_t)v, m, 64);
  int hi = __shfl_xor((int)(uint32_t)(v >> 32), m, 64);
  return ((uint64_t)(uint32_t)hi << 32) | (uint32_t)lo;
}

// neg_dist[n,m] as XLA-CPU evaluates it (q = row n, p = candidate m):
//   dot   = fma(qz,pz, fma(qy,py, qx*px))   (Eigen gemm k=3 FMA chain)
//   inner = -2.0f * dot                      (exact)
//   nd    = ((-p.w) - inner) - q.w           (neighbor norm first!)
__device__ __forceinline__ float nd_ref(const float4 q, const float4 p) {
  float dot = __builtin_fmaf(q.z, p.z, __builtin_fmaf(q.y, p.y, q.x * p.x));
  {
#pragma clang fp contract(off)
    float inner = -2.0f * dot;
    return ((-p.w) - inner) - q.w;
  }
}

__global__ __launch_bounds__(THREADS, 1) void knn_topk_kernel(
    const float* __restrict__ x, float* __restrict__ fout, float* __restrict__ iout) {
  __shared__ float4 xs[NPTS];            // 64 KB: (x0,x1,x2,xx)
  __shared__ uint64_t cbuf[WAVES][64];   // 4 KB compact buffers
  __shared__ int ccnt[WAVES];

  const int tid  = threadIdx.x;
  const int wave = tid >> 6;
  const int lane = tid & 63;
  const int b    = blockIdx.x >> 9;                       // 512 blocks per batch
  const int n    = ((blockIdx.x & 511) * WAVES) + wave;   // row within batch

  // ---- stage x[b] + squared norms: XLA reduce(x*x) over 3 elems:
  //      plain sequential adds of individually-rounded squares.
  const float* xb = x + (size_t)b * 3 * NPTS;
  for (int i = tid; i < NPTS; i += THREADS) {
#pragma clang fp contract(off)
    float x0 = xb[i], x1 = xb[NPTS + i], x2 = xb[2 * NPTS + i];
    float xx = (x0 * x0 + x1 * x1) + x2 * x2;
    xs[i] = make_float4(x0, x1, x2, xx);
  }
  cbuf[wave][lane] = 0ull;
  if (lane == 0) ccnt[wave] = 0;
  __syncthreads();

  float4 q = xs[n];

  uint32_t vals[64];
  uint32_t l0 = 0, l1 = 0, l2 = 0, l3 = 0, l4 = 0, l5 = 0, l6 = 0, l7 = 0;

  // ---- distances + per-lane sorted top-8 (branch-free min/max chain)
  #pragma unroll
  for (int j = 0; j < 64; ++j) {
    float4 p = xs[j * 64 + lane];
    uint32_t v = ordf(nd_ref(q, p));
    vals[j] = v;
    l7 = min(l6, max(l7, v));
    l6 = min(l5, max(l6, v));
    l5 = min(l4, max(l5, v));
    l4 = min(l3, max(l4, v));
    l3 = min(l2, max(l3, v));
    l2 = min(l1, max(l2, v));
    l1 = min(l0, max(l1, v));
    l0 = max(l0, v);
  }

  // ---- 20-round cross-lane merge of sorted lists -> T20 (20th largest key)
  // (union of per-lane top-8s: its 20th largest <= true 20th; compact re-scans
  //  vals[] so the compact set still contains the true top-20)
  int pos = 0;
  uint32_t T20 = 0;
  for (int r = 0; r < KSEL; ++r) {
    uint32_t a0 = (pos & 1) ? l1 : l0;
    uint32_t a1 = (pos & 1) ? l3 : l2;
    uint32_t a2 = (pos & 1) ? l5 : l4;
    uint32_t a3 = (pos & 1) ? l7 : l6;
    uint32_t b0 = (pos & 2) ? a1 : a0;
    uint32_t b1 = (pos & 2) ? a3 : a2;
    uint32_t h  = (pos & 4) ? b1 : b0;
    h = (pos >= 8) ? 0u : h;
    uint32_t g = h;
    #pragma unroll
    for (int mm = 1; mm <= 32; mm <<= 1)
      g = max(g, (uint32_t)__shfl_xor((int)g, mm, 64));
    unsigned long long bal = __ballot(h == g);
    int first = (int)__ffsll((long long)bal) - 1;
    pos += (lane == first) ? 1 : 0;
    T20 = g;
  }

  // ---- compact all candidates >= T20 (superset of the true top-20)
  #pragma unroll
  for (int j = 0; j < 64; ++j) {
    if (vals[j] >= T20) {
      int slot = atomicAdd(&ccnt[wave], 1);
      if (slot < 64) {
        uint32_t m = (uint32_t)(j * 64 + lane);
        cbuf[wave][slot] = ((uint64_t)vals[j] << 32) | (0xFFFFFFFFu - m);
      }
    }
  }
  __syncthreads();

  // ---- bitonic sort 64 keys descending (value desc, index asc on ties --
  //      matches stable lax.top_k tie-breaking)
  uint64_t key = cbuf[wave][lane];
  #pragma unroll
  for (int k = 2; k <= 64; k <<= 1) {
    #pragma unroll
    for (int j2 = k >> 1; j2 > 0; j2 >>= 1) {
      uint64_t o = shflx64(key, j2);
      bool keep_max = ((lane & k) == 0) == ((lane & j2) == 0);
      uint64_t mx = key > o ? key : o;
      uint64_t mn = key > o ? o : key;
      key = keep_max ? mx : mn;
    }
  }

  // ---- emit: feature_mean (stashed in o=0 plane) + idx_flat (as float!)
  if (lane < KSEL) {
#pragma clang fp contract(off)
    uint32_t m = 0xFFFFFFFFu - (uint32_t)key;
    float4 p = xs[m];
    float fm = ((p.x + p.y) + p.z) / 3.0f;  // mean: seq sum, then div
    fout[((size_t)(b * 64 + 0) * NPTS + n) * KSEL + lane] = fm;
    iout[((size_t)b * NPTS + n) * KSEL + lane] = (float)((int)m + b * NPTS);
  }
}

__global__ __launch_bounds__(256, 1) void expand_kernel(
    const float* __restrict__ W, float* __restrict__ out) {
  const int chunk = blockIdx.x;  // 0..79 : 1024-float chunk of the 81920 plane
  const int b     = blockIdx.y;  // 0..7
  const size_t PLANE = (size_t)NPTS * KSEL;  // 81920
  size_t base = (size_t)b * 64 * PLANE + (size_t)chunk * 1024 + threadIdx.x * 4;
  float4 v = *(const float4*)(out + base);  // fm stash at o=0
  #pragma unroll
  for (int o = 1; o < 64; ++o) {
    float w = W[o];
    *(float4*)(out + base + (size_t)o * PLANE) =
        make_float4(v.x * w, v.y * w, v.z * w, v.w * w);
  }
  float w0 = W[0];
  *(float4*)(out + base) = make_float4(v.x * w0, v.y * w0, v.z * w0, v.w * w0);
}

extern "C" void kernel_launch(void* const* d_in, const int* in_sizes, int n_in,
                              void* d_out, int out_size, void* d_ws, size_t ws_size,
                              hipStream_t stream) {
  const float* x = (const float*)d_in[0];
  const float* W = (const float*)d_in[1];
  float* fout = (float*)d_out;
  float* iout = (float*)d_out + (size_t)8 * 64 * NPTS * KSEL;

  knn_topk_kernel<<<dim3(8 * 512), dim3(THREADS), 0, stream>>>(x, fout, iout);
  expand_kernel<<<dim3(80, 8), dim3(256), 0, stream>>>(W, fout);
}